// Round 3
// baseline (857.077 us; speedup 1.0000x reference)
//
#include <hip/hip_runtime.h>
#include <hip/hip_bf16.h>
#include <math.h>

// Problem constants (B=1)
#define NW   162
#define WS   256
#define NH   8
#define HD   64
#define CC   512
#define NTOK 41472      // NW*WS
#define HID  2048

typedef __bf16 bf16x8 __attribute__((ext_vector_type(8)));
typedef float  floatx4 __attribute__((ext_vector_type(4)));

__device__ __forceinline__ void gload_lds16(const __bf16* g, __bf16* l) {
    __builtin_amdgcn_global_load_lds((const __attribute__((address_space(1))) void*)g,
                                     (__attribute__((address_space(3))) void*)l,
                                     16, 0, 0);
}
__device__ __forceinline__ float fast_rcp(float x) { return __builtin_amdgcn_rcpf(x); }

#define GBAR()  __builtin_amdgcn_s_barrier()
#define VMW(N)  asm volatile("s_waitcnt vmcnt(" #N ")" ::: "memory")
#define LGKM(N) asm volatile("s_waitcnt lgkmcnt(" #N ")" ::: "memory")
#define SCHED0() __builtin_amdgcn_sched_barrier(0)

// ---------------------------------------------------------------- perm build
// Any consistent intra-window order is exact (attention is permutation-
// equivariant within a window; output scattered back through pos).
__global__ __launch_bounds__(256)
void build_perm_atomic(const int* __restrict__ wid, int* __restrict__ perm,
                       int* __restrict__ pos, int* __restrict__ counters) {
    const int i = blockIdx.x * 256 + threadIdx.x;
    const int w = wid[i];
    const int r = atomicAdd(&counters[w], 1);
    perm[w * WS + r] = i;
    pos[i] = w * WS + r;
}

// ------------------------------------------------------- weight transpose
__global__ void transpose_bf16(const float* __restrict__ in,
                               __bf16* __restrict__ out, int K, int N) {
    int idx = blockIdx.x * 256 + threadIdx.x;
    if (idx >= K * N) return;
    int n = idx / K, k = idx - n * K;
    out[idx] = (__bf16)in[(size_t)k * N + n];
}

// ---------------------------------------------------------------- LN kernels
__global__ __launch_bounds__(64)
void ln1_gather(const float* __restrict__ x, const int* __restrict__ perm,
                const float* __restrict__ g, const float* __restrict__ b,
                __bf16* __restrict__ h) {
    const int j = blockIdx.x, lane = threadIdx.x;
    const int orig = perm[j];
    const float4* xp = (const float4*)(x + (size_t)orig * CC);
    float4 a0 = xp[lane * 2 + 0], a1 = xp[lane * 2 + 1];
    float s  = a0.x + a0.y + a0.z + a0.w + a1.x + a1.y + a1.z + a1.w;
    float sq = a0.x*a0.x + a0.y*a0.y + a0.z*a0.z + a0.w*a0.w
             + a1.x*a1.x + a1.y*a1.y + a1.z*a1.z + a1.w*a1.w;
#pragma unroll
    for (int o = 32; o; o >>= 1) { s += __shfl_xor(s, o); sq += __shfl_xor(sq, o); }
    const float m  = s * (1.f / CC);
    const float rs = rsqrtf(sq * (1.f / CC) - m * m + 1e-5f);
    const float4* g4 = (const float4*)g;  const float4* b4 = (const float4*)b;
    float4 g0 = g4[lane*2+0], g1 = g4[lane*2+1], bb0 = b4[lane*2+0], bb1 = b4[lane*2+1];
    bf16x8 o8;
    o8[0] = (__bf16)((a0.x - m) * rs * g0.x + bb0.x);
    o8[1] = (__bf16)((a0.y - m) * rs * g0.y + bb0.y);
    o8[2] = (__bf16)((a0.z - m) * rs * g0.z + bb0.z);
    o8[3] = (__bf16)((a0.w - m) * rs * g0.w + bb0.w);
    o8[4] = (__bf16)((a1.x - m) * rs * g1.x + bb1.x);
    o8[5] = (__bf16)((a1.y - m) * rs * g1.y + bb1.y);
    o8[6] = (__bf16)((a1.z - m) * rs * g1.z + bb1.z);
    o8[7] = (__bf16)((a1.w - m) * rs * g1.w + bb1.w);
    *(bf16x8*)(h + (size_t)j * CC + lane * 8) = o8;
}

__global__ __launch_bounds__(64)
void resid_ln2(const float* __restrict__ x, const float* __restrict__ ptmp,
               const int* __restrict__ pos, const float* __restrict__ g,
               const float* __restrict__ b, float* __restrict__ xout,
               __bf16* __restrict__ h2) {
    const int i = blockIdx.x, lane = threadIdx.x;
    const int p = pos[i];
    const float4* xp = (const float4*)(x + (size_t)i * CC);
    const float4* pp = (const float4*)(ptmp + (size_t)p * CC);
    float4 a0 = xp[lane*2+0], a1 = xp[lane*2+1];
    float4 t0 = pp[lane*2+0], t1 = pp[lane*2+1];
    a0.x += t0.x; a0.y += t0.y; a0.z += t0.z; a0.w += t0.w;
    a1.x += t1.x; a1.y += t1.y; a1.z += t1.z; a1.w += t1.w;
    float4* op = (float4*)(xout + (size_t)i * CC);
    op[lane*2+0] = a0; op[lane*2+1] = a1;
    float s  = a0.x + a0.y + a0.z + a0.w + a1.x + a1.y + a1.z + a1.w;
    float sq = a0.x*a0.x + a0.y*a0.y + a0.z*a0.z + a0.w*a0.w
             + a1.x*a1.x + a1.y*a1.y + a1.z*a1.z + a1.w*a1.w;
#pragma unroll
    for (int o = 32; o; o >>= 1) { s += __shfl_xor(s, o); sq += __shfl_xor(sq, o); }
    const float m  = s * (1.f / CC);
    const float rs = rsqrtf(sq * (1.f / CC) - m * m + 1e-5f);
    const float4* g4 = (const float4*)g;  const float4* b4 = (const float4*)b;
    float4 g0 = g4[lane*2+0], g1 = g4[lane*2+1], bb0 = b4[lane*2+0], bb1 = b4[lane*2+1];
    bf16x8 o8;
    o8[0] = (__bf16)((a0.x - m) * rs * g0.x + bb0.x);
    o8[1] = (__bf16)((a0.y - m) * rs * g0.y + bb0.y);
    o8[2] = (__bf16)((a0.z - m) * rs * g0.z + bb0.z);
    o8[3] = (__bf16)((a0.w - m) * rs * g0.w + bb0.w);
    o8[4] = (__bf16)((a1.x - m) * rs * g1.x + bb1.x);
    o8[5] = (__bf16)((a1.y - m) * rs * g1.y + bb1.y);
    o8[6] = (__bf16)((a1.z - m) * rs * g1.z + bb1.z);
    o8[7] = (__bf16)((a1.w - m) * rs * g1.w + bb1.w);
    *(bf16x8*)(h2 + (size_t)i * CC + lane * 8) = o8;
}

// ---------------------------------------------------------------- GEMM 256x256, 4-phase + read-ahead
// 8 waves (2M x 4N), BK=64, 128 KiB LDS (2-tile rotating buffer).
// LDS reads are software-pipelined ONE PHASE AHEAD (m196/m201 lever): phase p
// issues the ds_reads for phase p+1's fragments, then waits only the OLDER
// reads (counted lgkmcnt), so ds_read latency hides under the 16 MFMAs.
//   frag regs: af0 (A mh0, 8), af1 (A mh1, 8), b0 (B nh0, 4), b1 (B nh1, 4)
//   ph0: MFMA(af0,b0)  issue b1   (4)  LGKM(4)  [waits af0,b0 from prev ph3]
//   ph1: MFMA(af0,b1)  issue af1  (8)  LGKM(8)  [waits b1]
//   ph2: MFMA(af1,b1)  issue none      LGKM(0)  [waits af1]
//   ph3: MFMA(af1,b0)  issue af0(t+1) pre-MFMA, b0(t+1) post-MFMA (regs free)
// Staging (t+2 scheme, unchanged from r2): ph1 -> A0,B0(t+2) into CURRENT
// buffers; ph2 -> B1(t+2); ph3 -> A1(t+2).  VMW schedule unchanged:
// ph0 VMW(10) publishes B1(t) (read this phase, after the barrier);
// ph1 VMW(8) publishes A1(t); ph3 VMW(10) publishes A0,B0(t+1) (read-ahead
// this phase).  Each read batch is issued only after the VMW+barrier that
// publishes its set.  Slot-overwrite safety: every stage targets a slot whose
// reads were issued >=2 phases earlier and completed before an intervening
// barrier (verified per set).  XOR chunk swizzle (chunk ^= row&7) on staging
// source and frag reads — conflict-free (SQ_LDS_BANK_CONFLICT == 0 measured).
__device__ __forceinline__ void stage_A(const __bf16* __restrict__ g, int K, int kcol,
                                        __bf16* lds, int h, int tid, int wave) {
    const int sch = ((tid & 7) ^ ((tid >> 3) & 7)) << 3;
#pragma unroll
    for (int j = 0; j < 2; j++) {
        const int rw   = (j * 512 + tid) >> 3;
        const int row  = (rw & 63) + ((rw & 64) << 1) + (h << 6);
        const int rw0  = j * 64 + wave * 8;
        const int row0 = (rw0 & 63) + ((rw0 & 64) << 1) + (h << 6);
        gload_lds16(g + (size_t)row * K + kcol + sch, lds + row0 * 64);
    }
}
__device__ __forceinline__ void stage_B(const __bf16* __restrict__ g, int K, int kcol,
                                        __bf16* lds, int h, int tid, int wave) {
    const int sch = ((tid & 7) ^ ((tid >> 3) & 7)) << 3;
#pragma unroll
    for (int j = 0; j < 2; j++) {
        const int rw   = (j * 512 + tid) >> 3;
        const int row  = (rw & 31) + ((rw >> 5) << 6) + (h << 5);
        const int rw0  = j * 64 + wave * 8;
        const int row0 = (rw0 & 31) + ((rw0 >> 5) << 6) + (h << 5);
        gload_lds16(g + (size_t)row * K + kcol + sch, lds + row0 * 64);
    }
}

__device__ __forceinline__ void load_afr(const __bf16* buf, int wm, int mh,
                                         int lr, int lq, bf16x8 (&af)[4][2]) {
#pragma unroll
    for (int mt = 0; mt < 4; mt++) {
        const __bf16* rp = buf + (wm * 128 + mh * 64 + mt * 16 + lr) * 64;
#pragma unroll
        for (int kk = 0; kk < 2; kk++)
            af[mt][kk] = *(const bf16x8*)(rp + (((kk * 4 + lq) ^ (lr & 7)) << 3));
    }
}
__device__ __forceinline__ void load_bfr(const __bf16* buf, int wn, int nh,
                                         int lr, int lq, bf16x8 (&bf)[2][2]) {
#pragma unroll
    for (int nt = 0; nt < 2; nt++) {
        const __bf16* rp = buf + (wn * 64 + nh * 32 + nt * 16 + lr) * 64;
#pragma unroll
        for (int kk = 0; kk < 2; kk++)
            bf[nt][kk] = *(const bf16x8*)(rp + (((kk * 4 + lq) ^ (lr & 7)) << 3));
    }
}

#define MFMA_QUAD(MH, NH, AF, BF)                                              \
    _Pragma("unroll") for (int kk_ = 0; kk_ < 2; kk_++)                        \
    _Pragma("unroll") for (int mt_ = 0; mt_ < 4; mt_++)                        \
    _Pragma("unroll") for (int nt_ = 0; nt_ < 2; nt_++)                        \
        acc[(MH) * 4 + mt_][(NH) * 2 + nt_] =                                  \
            __builtin_amdgcn_mfma_f32_16x16x32_bf16(                           \
                AF[mt_][kk_], BF[nt_][kk_],                                    \
                acc[(MH) * 4 + mt_][(NH) * 2 + nt_], 0, 0, 0);

// EPI: 0 = +bias -> bf16; 1 = +bias -> f32; 2 = +bias, GELU(logistic) -> bf16;
//      3 = res + acc + bias -> f32.
template <int EPI>
__global__ __launch_bounds__(512, 2)
void gemm256(const __bf16* __restrict__ A, const __bf16* __restrict__ Bt,
             const float* __restrict__ bias, const float* __restrict__ res,
             float* __restrict__ Cf, __bf16* __restrict__ Cb,
             int M, int N, int K) {
    __shared__ __bf16 smem[65536];   // 128 KiB: A dbuf 64K | B dbuf 64K; epilogue reuses as C-tile
    __bf16* Ac = smem;
    __bf16* An = smem + 16384;
    __bf16* Bc = smem + 32768;
    __bf16* Bn = smem + 49152;

    const int tid  = threadIdx.x;
    const int wave = tid >> 6;
    const int lane = tid & 63;
    const int wm = wave >> 2, wn = wave & 3;
    const int lr = lane & 15, lq = lane >> 4;

    // bijective XCD-aware swizzle (m204 form; grids here are not all %8==0)
    const int gx  = gridDim.x;
    const int nwg = gx * gridDim.y;
    const int orig = blockIdx.y * gx + blockIdx.x;
    const int q8 = nwg >> 3, r8 = nwg & 7;
    const int xcd = orig & 7, oi = orig >> 3;
    const int wgid = (xcd < r8 ? xcd * (q8 + 1) : r8 * (q8 + 1) + (xcd - r8) * q8) + oi;
    const int bm = wgid / gx, bn = wgid - bm * gx;

    const __bf16* gA = A  + (size_t)bm * 256 * K;
    const __bf16* gB = Bt + (size_t)bn * 256 * K;
    const int NT = K >> 6;   // >= 8 for every GEMM in this block

    floatx4 acc[8][4];
#pragma unroll
    for (int i = 0; i < 8; i++)
#pragma unroll
        for (int j = 0; j < 4; j++) acc[i][j] = (floatx4){0.f, 0.f, 0.f, 0.f};

    // prologue: canonical per-tile issue order (A0,B0,B1,A1), tiles 0 and 1.
    // VMW(10) (14 outstanding) completes A0(0),B0(0); barrier publishes them;
    // then the tile-0 ph0 fragments are read ahead of the loop.
    stage_A(gA, K, 0, Ac, 0, tid, wave);
    stage_B(gB, K, 0, Bc, 0, tid, wave);
    stage_B(gB, K, 0, Bc, 1, tid, wave);
    stage_A(gA, K, 0, Ac, 1, tid, wave);
    stage_A(gA, K, 64, An, 0, tid, wave);
    stage_B(gB, K, 64, Bn, 0, tid, wave);
    stage_B(gB, K, 64, Bn, 1, tid, wave);
    VMW(10);
    stage_A(gA, K, 64, An, 1, tid, wave);
    GBAR();

    bf16x8 af0[4][2], af1[4][2], b0[2][2], b1[2][2];
    load_afr(Ac, wm, 0, lr, lq, af0);    // 12 reads in flight entering the loop
    load_bfr(Bc, wn, 0, lr, lq, b0);

    for (int t = 0; t < NT; t++) {
        const int k2 = (t + 2) << 6;
        const bool sN = (t < NT - 2);
        // ---- phase 0: MFMA (mh0,nh0).  VMW(10) publishes B1(t); after the
        //      barrier issue b1 reads, wait the 12 older (af0,b0), leave 4.
        if (t < NT - 1) { VMW(10); } else { VMW(2); }
        GBAR();
        load_bfr(Bc, wn, 1, lr, lq, b1);
        LGKM(4); SCHED0();
        __builtin_amdgcn_s_setprio(1);
        MFMA_QUAD(0, 0, af0, b0);
        __builtin_amdgcn_s_setprio(0);
        GBAR();
        // ---- phase 1: MFMA (mh0,nh1).  VMW(8) publishes A1(t); stage
        //      A0,B0(t+2) into CURRENT buffers (slots' reads were issued at
        //      t-1.ph3 and completed before ph0's MFMA barrier-pair).
        //      Issue af1 reads, wait b1's 4, leave 8.
        if (t < NT - 1) { VMW(8); } else { VMW(0); }
        if (sN) {
            stage_A(gA, K, k2, Ac, 0, tid, wave);
            stage_B(gB, K, k2, Bc, 0, tid, wave);
        }
        GBAR();
        load_afr(Ac, wm, 1, lr, lq, af1);
        LGKM(8); SCHED0();
        __builtin_amdgcn_s_setprio(1);
        MFMA_QUAD(0, 1, af0, b1);
        __builtin_amdgcn_s_setprio(0);
        GBAR();
        // ---- phase 2: MFMA (mh1,nh1).  stage B1(t+2) (slot read at ph0,
        //      completed before ph1's MFMA).  Wait af1's 8.
        if (sN) stage_B(gB, K, k2, Bc, 1, tid, wave);
        GBAR();
        LGKM(0); SCHED0();
        __builtin_amdgcn_s_setprio(1);
        MFMA_QUAD(1, 1, af1, b1);
        __builtin_amdgcn_s_setprio(0);
        GBAR();
        // ---- phase 3: MFMA (mh1,nh0).  VMW(10) publishes A0,B0(t+1); stage
        //      A1(t+2).  Read-ahead af0(t+1) before the MFMAs (regs free since
        //      ph1), b0(t+1) after (regs freed by this quad).  No LGKM: this
        //      quad's operands are already in registers.
        if (sN) { VMW(10); } else { VMW(4); }
        if (sN) stage_A(gA, K, k2, Ac, 1, tid, wave);
        GBAR();
        if (t + 1 < NT) load_afr(An, wm, 0, lr, lq, af0);
        SCHED0();
        __builtin_amdgcn_s_setprio(1);
        MFMA_QUAD(1, 0, af1, b0);
        __builtin_amdgcn_s_setprio(0);
        if (t + 1 < NT) load_bfr(Bn, wn, 0, lr, lq, b0);
        GBAR();
        // rotate 2-tile buffers
        __bf16* ta = Ac; Ac = An; An = ta;
        __bf16* tb = Bc; Bc = Bn; Bn = tb;
    }

    if constexpr (EPI == 0 || EPI == 2) {
        // repack through LDS (reuse the 128 KiB as a [256][256] bf16 C-tile)
        __bf16* Ct = smem;
#pragma unroll
        for (int m = 0; m < 8; m++)
#pragma unroll
            for (int n = 0; n < 4; n++) {
                const int col = wn * 64 + n * 16 + lr;
                const float bv = bias[bn * 256 + col];
#pragma unroll
                for (int r = 0; r < 4; r++) {
                    float v = acc[m][n][r] + bv;
                    if constexpr (EPI == 2) {
                        // gelu ~= v * sigmoid(1.702 v); pre-act sigma~0.45 so
                        // logistic-vs-erf error is ~1e-3 after W2 contraction
                        const float e = __expf(v * -1.702f);
                        v = v * fast_rcp(1.f + e);
                    }
                    Ct[(wm * 128 + m * 16 + lq * 4 + r) * 256 + col] = (__bf16)v;
                }
            }
        __syncthreads();
#pragma unroll
        for (int j = 0; j < 16; j++) {
            const int ci = j * 512 + tid;
            const int row = ci >> 5, ch = ci & 31;
            *(bf16x8*)(Cb + (size_t)(bm * 256 + row) * N + bn * 256 + ch * 8) =
                *(const bf16x8*)(Ct + row * 256 + ch * 8);
        }
    } else {
#pragma unroll
        for (int m = 0; m < 8; m++) {
            const int row = bm * 256 + wm * 128 + m * 16 + lq * 4;
#pragma unroll
            for (int n = 0; n < 4; n++) {
                const int col = bn * 256 + wn * 64 + n * 16 + lr;
                const float bv = bias[col];
#pragma unroll
                for (int r = 0; r < 4; r++) {
                    const float v = acc[m][n][r] + bv;
                    const size_t off = (size_t)(row + r) * N + col;
                    if constexpr (EPI == 1) Cf[off] = v;
                    else                    Cf[off] = res[off] + v;
                }
            }
        }
    }
}

// ---------------------------------------------------------------- attention (MFMA)
// One block per (window, head), 4 waves x 64 q-rows. ONE barrier total (after
// V staging): pbuf is wave-private and cross-lane LDS traffic within a wave
// is ordered by lgkmcnt — no __syncthreads needed in the K-loop or epilogue.
// V is stored TRANSPOSED in LDS with an XOR swizzle on the key-block index so
// PV B-frags are 4x ds_read_b128 per kt (uniform bank spread) instead of 32
// scalar reads. K fragments are software-prefetched one kt ahead.
__global__ __launch_bounds__(256)
void attn_mfma(const __bf16* __restrict__ qkv, __bf16* __restrict__ aout,
               const float* __restrict__ rel_bias) {
    __shared__ __bf16 vsT[HD * WS];      // [d][key-swizzled], 32 KB
    __shared__ __bf16 pbuf[4][64][34];   // wave-private P tile
    const int w = blockIdx.x, h = blockIdx.y;
    const int tid = threadIdx.x;
    const int wave = tid >> 6, lane = tid & 63;
    const int lr = lane & 15, lq = lane >> 4;
    const size_t base = (size_t)w * (WS * 1536) + h * 64;

    // stage V transposed: coalesced global bf16x8 reads, scalar swizzled LDS writes
    for (int c = tid; c < WS * 8; c += 256) {
        const int key = c >> 3, d8 = c & 7;
        bf16x8 vv = *(const bf16x8*)(qkv + base + 1024 + (size_t)key * 1536 + d8 * 8);
#pragma unroll
        for (int jj = 0; jj < 8; jj++) {
            const int d = d8 * 8 + jj;
            vsT[d * WS + (((key >> 3) ^ (d & 31)) << 3) + (key & 7)] = vv[jj];
        }
    }

    const int q0 = wave * 64;
    bf16x8 qf[4][2];
#pragma unroll
    for (int mt = 0; mt < 4; mt++)
#pragma unroll
        for (int kk = 0; kk < 2; kk++)
            qf[mt][kk] = *(const bf16x8*)(qkv + base +
                (size_t)(q0 + mt * 16 + lr) * 1536 + kk * 32 + lq * 8);

    __syncthreads();   // the only block-wide barrier

    floatx4 o[4][4];
    float lsum[4][4];
#pragma unroll
    for (int mt = 0; mt < 4; mt++)
#pragma unroll
        for (int dt = 0; dt < 4; dt++) o[mt][dt] = (floatx4){0.f, 0.f, 0.f, 0.f};
#pragma unroll
    for (int mt = 0; mt < 4; mt++)
#pragma unroll
        for (int r = 0; r < 4; r++) lsum[mt][r] = 0.f;

    const float sc = 0.125f * 1.44269504089f;
    const float bb = rel_bias[h] * 1.44269504089f;
    const __bf16* kp0 = qkv + base + 512;

    // prefetch kt=0 K-frags
    bf16x8 kc[2][2];
#pragma unroll
    for (int nt = 0; nt < 2; nt++) {
        const __bf16* kp = kp0 + (size_t)(nt * 16 + lr) * 1536 + lq * 8;
        kc[nt][0] = *(const bf16x8*)(kp);
        kc[nt][1] = *(const bf16x8*)(kp + 32);
    }

    for (int kt = 0; kt < 8; kt++) {
        const int kbase = kt * 32;
        bf16x8 kn[2][2];
        if (kt < 7) {
#pragma unroll
            for (int nt = 0; nt < 2; nt++) {
                const __bf16* kp = kp0 + (size_t)(kbase + 32 + nt * 16 + lr) * 1536 + lq * 8;
                kn[nt][0] = *(const bf16x8*)(kp);
                kn[nt][1] = *(const bf16x8*)(kp + 32);
            }
        }
        floatx4 s[4][2];
#pragma unroll
        for (int mt = 0; mt < 4; mt++)
#pragma unroll
            for (int nt = 0; nt < 2; nt++) s[mt][nt] = (floatx4){0.f, 0.f, 0.f, 0.f};
#pragma unroll
        for (int nt = 0; nt < 2; nt++)
#pragma unroll
            for (int mt = 0; mt < 4; mt++) {
                s[mt][nt] = __builtin_amdgcn_mfma_f32_16x16x32_bf16(qf[mt][0], kc[nt][0], s[mt][nt], 0, 0, 0);
                s[mt][nt] = __builtin_amdgcn_mfma_f32_16x16x32_bf16(qf[mt][1], kc[nt][1], s[mt][nt], 0, 0, 0);
            }
#pragma unroll
        for (int mt = 0; mt < 4; mt++)
#pragma unroll
            for (int nt = 0; nt < 2; nt++)
#pragma unroll
                for (int r = 0; r < 4; r++) {
                    float e = exp2f(s[mt][nt][r] * sc + bb);
                    lsum[mt][r] += e;
                    pbuf[wave][mt * 16 + lq * 4 + r][nt * 16 + lr] = (__bf16)e;
                }
        // V B-frags: vf[dt][j] = V[kbase+lq*8+j][dt*16+lr] via swizzled vsT
        bf16x8 vf[4];
#pragma unroll
        for (int dt = 0; dt < 4; dt++) {
            const int d = dt * 16 + lr;
            vf[dt] = *(const bf16x8*)(vsT + d * WS +
                                      (((kt * 4 + lq) ^ (d & 31)) << 3));
        }
#pragma unroll
        for (int mt = 0; mt < 4; mt++) {
            bf16x8 pf = *(const bf16x8*)(&pbuf[wave][mt * 16 + lr][lq * 8]);
#pragma unroll
            for (int dt = 0; dt < 4; dt++)
                o[mt][dt] = __builtin_amdgcn_mfma_f32_16x16x32_bf16(pf, vf[dt], o[mt][dt], 0, 0, 0);
        }
#pragma unroll
        for (int nt = 0; nt < 2; nt++) { kc[nt][0] = kn[nt][0]; kc[nt][1] = kn[nt][1]; }
    }

#pragma unroll
    for (int mt = 0; mt < 4; mt++)
#pragma unroll
        for (int r = 0; r < 4; r++) {
            float v = lsum[mt][r];
            v += __shfl_xor(v, 1); v += __shfl_xor(v, 2);
            v += __shfl_xor(v, 4); v += __shfl_xor(v, 8);
            lsum[mt][r] = fast_rcp(v);
        }

    // scale + repack through wave-private pbuf (no barriers needed)
#pragma unroll
    for (int dh = 0; dh < 2; dh++) {
#pragma unroll
        for (int mt = 0; mt < 4; mt++)
#pragma unroll
            for (int dt = 0; dt < 2; dt++)
#pragma unroll
                for (int r = 0; r < 4; r++)
                    pbuf[wave][mt * 16 + lq * 4 + r][dt * 16 + lr] =
                        (__bf16)(o[mt][dh * 2 + dt][r] * lsum[mt][r]);
#pragma unroll
        for (int it = 0; it < 4; it++) {
            const int c = it * 64 + lane;
            const int row = c >> 2, seg = c & 3;
            bf16x8 val = *(const bf16x8*)(&pbuf[wave][row][seg * 8]);
            *(bf16x8*)(aout + (size_t)(w * WS + q0 + row) * CC + h * 64 + dh * 32 + seg * 8) = val;
        }
    }
}

// ---------------------------------------------------------------- launch
extern "C" void kernel_launch(void* const* d_in, const int* in_sizes, int n_in,
                              void* d_out, int out_size, void* d_ws, size_t ws_size,
                              hipStream_t stream) {
    const float* x      = (const float*)d_in[0];
    const float* mesh   = (const float*)d_in[1];
    const float* ln1_g  = (const float*)d_in[2];
    const float* ln1_b  = (const float*)d_in[3];
    const float* qkv_w  = (const float*)d_in[4];
    const float* qkv_b  = (const float*)d_in[5];
    const float* rel_b  = (const float*)d_in[6];
    const float* proj_w = (const float*)d_in[7];
    const float* proj_b = (const float*)d_in[8];
    const float* ln2_g  = (const float*)d_in[9];
    const float* ln2_b  = (const float*)d_in[10];
    const float* w1     = (const float*)d_in[11];
    const float* b1     = (const float*)d_in[12];
    const float* w2     = (const float*)d_in[13];
    const float* b2     = (const float*)d_in[14];
    const int*   wid    = (const int*)d_in[15];

    char* ws = (char*)d_ws;
    int*    perm  = (int*)(ws + 0);
    int*    pos   = (int*)(ws + 165888);
    __bf16* wqkv  = (__bf16*)(ws + 331776);
    __bf16* wproj = (__bf16*)(ws + 1904640);
    __bf16* w1t   = (__bf16*)(ws + 2428928);
    __bf16* w2t   = (__bf16*)(ws + 4526080);
    const size_t BB = 6623232;
    __bf16* hln1 = (__bf16*)(ws + BB);
    __bf16* qkv  = (__bf16*)(ws + BB + 42467328);
    __bf16* aout = (__bf16*)(ws + BB + 169869312);
    float*  ptmp = (float*)(ws + BB);
    __bf16* h2   = (__bf16*)(ws + BB + 84934656);
    __bf16* f1   = (__bf16*)(ws + BB + 127401984);
    float*  xout = (float*)d_out;
    int*    counters = (int*)aout;   // dead region until attention writes aout

    hipMemsetAsync(counters, 0, NW * sizeof(int), stream);
    build_perm_atomic<<<NTOK / 256, 256, 0, stream>>>(wid, perm, pos, counters);

    transpose_bf16<<<(512 * 1536 + 255) / 256, 256, 0, stream>>>(qkv_w, wqkv, 512, 1536);
    transpose_bf16<<<(512 * 512 + 255) / 256, 256, 0, stream>>>(proj_w, wproj, 512, 512);
    transpose_bf16<<<(512 * 2048 + 255) / 256, 256, 0, stream>>>(w1, w1t, 512, 2048);
    transpose_bf16<<<(2048 * 512 + 255) / 256, 256, 0, stream>>>(w2, w2t, 2048, 512);

    ln1_gather<<<NTOK, 64, 0, stream>>>(x, perm, ln1_g, ln1_b, hln1);

    gemm256<0><<<dim3(1536 / 256, NTOK / 256), 512, 0, stream>>>(
        hln1, wqkv, qkv_b, nullptr, nullptr, qkv, NTOK, 1536, 512);

    attn_mfma<<<dim3(NW, NH), 256, 0, stream>>>(qkv, aout, rel_b);

    gemm256<1><<<dim3(512 / 256, NTOK / 256), 512, 0, stream>>>(
        aout, wproj, proj_b, nullptr, ptmp, nullptr, NTOK, 512, 512);

    resid_ln2<<<NTOK, 64, 0, stream>>>(x, ptmp, pos, ln2_g, ln2_b, xout, h2);

    gemm256<2><<<dim3(2048 / 256, NTOK / 256), 512, 0, stream>>>(
        h2, w1t, b1, nullptr, nullptr, f1, NTOK, 2048, 512);

    gemm256<3><<<dim3(512 / 256, NTOK / 256), 512, 0, stream>>>(
        f1, w2t, b2, xout, xout, nullptr, NTOK, 512, 2048);

    hipMemcpyAsync((char*)d_out + (size_t)NTOK * CC * 4, mesh,
                   (size_t)NTOK * 3 * 4, hipMemcpyDeviceToDevice, stream);
}

// Round 4
// 764.537 us; speedup vs baseline: 1.1210x; 1.1210x over previous
//
#include <hip/hip_runtime.h>
#include <hip/hip_bf16.h>
#include <math.h>

// Problem constants (B=1)
#define NW   162
#define WS   256
#define NH   8
#define HD   64
#define CC   512
#define NTOK 41472      // NW*WS
#define HID  2048

typedef __bf16 bf16x8 __attribute__((ext_vector_type(8)));
typedef float  floatx4 __attribute__((ext_vector_type(4)));

__device__ __forceinline__ void gload_lds16(const __bf16* g, __bf16* l) {
    __builtin_amdgcn_global_load_lds((const __attribute__((address_space(1))) void*)g,
                                     (__attribute__((address_space(3))) void*)l,
                                     16, 0, 0);
}
__device__ __forceinline__ float fast_rcp(float x) { return __builtin_amdgcn_rcpf(x); }

#define GBAR()  __builtin_amdgcn_s_barrier()
#define VMW(N)  asm volatile("s_waitcnt vmcnt(" #N ")" ::: "memory")
#define LGKM0() asm volatile("s_waitcnt lgkmcnt(0)" ::: "memory")
#define SCHED0() __builtin_amdgcn_sched_barrier(0)

// ---------------------------------------------------------------- perm build
// Any consistent intra-window order is exact (attention is permutation-
// equivariant within a window; output scattered back through perm).
__global__ __launch_bounds__(256)
void build_perm_atomic(const int* __restrict__ wid, int* __restrict__ perm,
                       int* __restrict__ pos, int* __restrict__ counters) {
    const int i = blockIdx.x * 256 + threadIdx.x;
    const int w = wid[i];
    const int r = atomicAdd(&counters[w], 1);
    perm[w * WS + r] = i;
    pos[i] = w * WS + r;
}

// ------------------------------------------------------- weight transpose
__global__ void transpose_bf16(const float* __restrict__ in,
                               __bf16* __restrict__ out, int K, int N) {
    int idx = blockIdx.x * 256 + threadIdx.x;
    if (idx >= K * N) return;
    int n = idx / K, k = idx - n * K;
    out[idx] = (__bf16)in[(size_t)k * N + n];
}

// ---------------------------------------------------------------- LN kernels
__global__ __launch_bounds__(64)
void ln1_gather(const float* __restrict__ x, const int* __restrict__ perm,
                const float* __restrict__ g, const float* __restrict__ b,
                __bf16* __restrict__ h) {
    const int j = blockIdx.x, lane = threadIdx.x;
    const int orig = perm[j];
    const float4* xp = (const float4*)(x + (size_t)orig * CC);
    float4 a0 = xp[lane * 2 + 0], a1 = xp[lane * 2 + 1];
    float s  = a0.x + a0.y + a0.z + a0.w + a1.x + a1.y + a1.z + a1.w;
    float sq = a0.x*a0.x + a0.y*a0.y + a0.z*a0.z + a0.w*a0.w
             + a1.x*a1.x + a1.y*a1.y + a1.z*a1.z + a1.w*a1.w;
#pragma unroll
    for (int o = 32; o; o >>= 1) { s += __shfl_xor(s, o); sq += __shfl_xor(sq, o); }
    const float m  = s * (1.f / CC);
    const float rs = rsqrtf(sq * (1.f / CC) - m * m + 1e-5f);
    const float4* g4 = (const float4*)g;  const float4* b4 = (const float4*)b;
    float4 g0 = g4[lane*2+0], g1 = g4[lane*2+1], bb0 = b4[lane*2+0], bb1 = b4[lane*2+1];
    bf16x8 o8;
    o8[0] = (__bf16)((a0.x - m) * rs * g0.x + bb0.x);
    o8[1] = (__bf16)((a0.y - m) * rs * g0.y + bb0.y);
    o8[2] = (__bf16)((a0.z - m) * rs * g0.z + bb0.z);
    o8[3] = (__bf16)((a0.w - m) * rs * g0.w + bb0.w);
    o8[4] = (__bf16)((a1.x - m) * rs * g1.x + bb1.x);
    o8[5] = (__bf16)((a1.y - m) * rs * g1.y + bb1.y);
    o8[6] = (__bf16)((a1.z - m) * rs * g1.z + bb1.z);
    o8[7] = (__bf16)((a1.w - m) * rs * g1.w + bb1.w);
    *(bf16x8*)(h + (size_t)j * CC + lane * 8) = o8;
}

// LN over xout (which already holds x + proj residual), writes bf16 h2.
__global__ __launch_bounds__(64)
void ln2_only(const float* __restrict__ x, const float* __restrict__ g,
              const float* __restrict__ b, __bf16* __restrict__ h2) {
    const int i = blockIdx.x, lane = threadIdx.x;
    const float4* xp = (const float4*)(x + (size_t)i * CC);
    float4 a0 = xp[lane*2+0], a1 = xp[lane*2+1];
    float s  = a0.x + a0.y + a0.z + a0.w + a1.x + a1.y + a1.z + a1.w;
    float sq = a0.x*a0.x + a0.y*a0.y + a0.z*a0.z + a0.w*a0.w
             + a1.x*a1.x + a1.y*a1.y + a1.z*a1.z + a1.w*a1.w;
#pragma unroll
    for (int o = 32; o; o >>= 1) { s += __shfl_xor(s, o); sq += __shfl_xor(sq, o); }
    const float m  = s * (1.f / CC);
    const float rs = rsqrtf(sq * (1.f / CC) - m * m + 1e-5f);
    const float4* g4 = (const float4*)g;  const float4* b4 = (const float4*)b;
    float4 g0 = g4[lane*2+0], g1 = g4[lane*2+1], bb0 = b4[lane*2+0], bb1 = b4[lane*2+1];
    bf16x8 o8;
    o8[0] = (__bf16)((a0.x - m) * rs * g0.x + bb0.x);
    o8[1] = (__bf16)((a0.y - m) * rs * g0.y + bb0.y);
    o8[2] = (__bf16)((a0.z - m) * rs * g0.z + bb0.z);
    o8[3] = (__bf16)((a0.w - m) * rs * g0.w + bb0.w);
    o8[4] = (__bf16)((a1.x - m) * rs * g1.x + bb1.x);
    o8[5] = (__bf16)((a1.y - m) * rs * g1.y + bb1.y);
    o8[6] = (__bf16)((a1.z - m) * rs * g1.z + bb1.z);
    o8[7] = (__bf16)((a1.w - m) * rs * g1.w + bb1.w);
    *(bf16x8*)(h2 + (size_t)i * CC + lane * 8) = o8;
}

// ---------------------------------------------------------------- GEMM 256x256 (r1 schedule)
// 8 waves (2M x 4N), BK=64, 128 KiB LDS (double buffer).  Best-measured
// schedule (round-1): per tile 4 phases, VMW(4) at ph0/ph1/ph3, staging one
// set per phase ~3 phases ahead.  XOR chunk swizzle (chunk ^= row&7) on
// staging source and frag reads — conflict-free (SQ_LDS_BANK_CONFLICT == 0).
__device__ __forceinline__ void stage_A(const __bf16* __restrict__ g, int K, int kcol,
                                        __bf16* lds, int h, int tid, int wave) {
    const int sch = ((tid & 7) ^ ((tid >> 3) & 7)) << 3;
#pragma unroll
    for (int j = 0; j < 2; j++) {
        const int rw   = (j * 512 + tid) >> 3;
        const int row  = (rw & 63) + ((rw & 64) << 1) + (h << 6);
        const int rw0  = j * 64 + wave * 8;
        const int row0 = (rw0 & 63) + ((rw0 & 64) << 1) + (h << 6);
        gload_lds16(g + (size_t)row * K + kcol + sch, lds + row0 * 64);
    }
}
__device__ __forceinline__ void stage_B(const __bf16* __restrict__ g, int K, int kcol,
                                        __bf16* lds, int h, int tid, int wave) {
    const int sch = ((tid & 7) ^ ((tid >> 3) & 7)) << 3;
#pragma unroll
    for (int j = 0; j < 2; j++) {
        const int rw   = (j * 512 + tid) >> 3;
        const int row  = (rw & 31) + ((rw >> 5) << 6) + (h << 5);
        const int rw0  = j * 64 + wave * 8;
        const int row0 = (rw0 & 31) + ((rw0 >> 5) << 6) + (h << 5);
        gload_lds16(g + (size_t)row * K + kcol + sch, lds + row0 * 64);
    }
}

__device__ __forceinline__ void load_afr(const __bf16* buf, int wm, int mh,
                                         int lr, int lq, bf16x8 (&af)[4][2]) {
#pragma unroll
    for (int mt = 0; mt < 4; mt++) {
        const __bf16* rp = buf + (wm * 128 + mh * 64 + mt * 16 + lr) * 64;
#pragma unroll
        for (int kk = 0; kk < 2; kk++)
            af[mt][kk] = *(const bf16x8*)(rp + (((kk * 4 + lq) ^ (lr & 7)) << 3));
    }
}
__device__ __forceinline__ void load_bfr(const __bf16* buf, int wn, int nh,
                                         int lr, int lq, bf16x8 (&bf)[2][2]) {
#pragma unroll
    for (int nt = 0; nt < 2; nt++) {
        const __bf16* rp = buf + (wn * 64 + nh * 32 + nt * 16 + lr) * 64;
#pragma unroll
        for (int kk = 0; kk < 2; kk++)
            bf[nt][kk] = *(const bf16x8*)(rp + (((kk * 4 + lq) ^ (lr & 7)) << 3));
    }
}

#define MFMA_QUAD(MH, NH, AF, BF)                                              \
    _Pragma("unroll") for (int kk_ = 0; kk_ < 2; kk_++)                        \
    _Pragma("unroll") for (int mt_ = 0; mt_ < 4; mt_++)                        \
    _Pragma("unroll") for (int nt_ = 0; nt_ < 2; nt_++)                        \
        acc[(MH) * 4 + mt_][(NH) * 2 + nt_] =                                  \
            __builtin_amdgcn_mfma_f32_16x16x32_bf16(                           \
                AF[mt_][kk_], BF[nt_][kk_],                                    \
                acc[(MH) * 4 + mt_][(NH) * 2 + nt_], 0, 0, 0);

// EPI: 0 = +bias -> bf16; 1 = +bias -> f32; 2 = +bias, GELU(logistic) -> bf16;
//      3 = res + acc + bias -> f32 (in-place residual);
//      4 = gathered residual: Cf[perm[row]] = res[perm[row]] + acc + bias.
template <int EPI>
__global__ __launch_bounds__(512, 2)
void gemm256(const __bf16* __restrict__ A, const __bf16* __restrict__ Bt,
             const float* __restrict__ bias, const float* __restrict__ res,
             float* __restrict__ Cf, __bf16* __restrict__ Cb,
             int M, int N, int K, const int* __restrict__ prm) {
    __shared__ __bf16 smem[65536];   // 128 KiB: A dbuf 64K | B dbuf 64K; epilogue reuses as C-tile
    __bf16* Ac = smem;
    __bf16* An = smem + 16384;
    __bf16* Bc = smem + 32768;
    __bf16* Bn = smem + 49152;

    const int tid  = threadIdx.x;
    const int wave = tid >> 6;
    const int lane = tid & 63;
    const int wm = wave >> 2, wn = wave & 3;
    const int lr = lane & 15, lq = lane >> 4;

    // bijective XCD-aware swizzle (m204 form; grids here are not all %8==0)
    const int gx  = gridDim.x;
    const int nwg = gx * gridDim.y;
    const int orig = blockIdx.y * gx + blockIdx.x;
    const int q8 = nwg >> 3, r8 = nwg & 7;
    const int xcd = orig & 7, oi = orig >> 3;
    const int wgid = (xcd < r8 ? xcd * (q8 + 1) : r8 * (q8 + 1) + (xcd - r8) * q8) + oi;
    const int bm = wgid / gx, bn = wgid - bm * gx;

    const __bf16* gA = A  + (size_t)bm * 256 * K;
    const __bf16* gB = Bt + (size_t)bn * 256 * K;
    const int NT = K >> 6;

    floatx4 acc[8][4];
#pragma unroll
    for (int i = 0; i < 8; i++)
#pragma unroll
        for (int j = 0; j < 4; j++) acc[i][j] = (floatx4){0.f, 0.f, 0.f, 0.f};

    // prologue (issue order defines vmcnt window): A0(0),B0(0),B1(0),A1(0),A0(1)
    stage_A(gA, K, 0, Ac, 0, tid, wave);
    stage_B(gB, K, 0, Bc, 0, tid, wave);
    stage_B(gB, K, 0, Bc, 1, tid, wave);
    stage_A(gA, K, 0, Ac, 1, tid, wave);
    if (NT > 1) stage_A(gA, K, 64, An, 0, tid, wave);
    VMW(4);
    GBAR();

    bf16x8 af[4][2], b0[2][2], b1[2][2];

    for (int t = 0; t < NT; t++) {
        const int k1 = (t + 1) << 6;
        // ---- phase 0: quad (mh0, nh0); stage B0(t+1)
        if (t == NT - 1) { VMW(0); } else { VMW(4); }
        if (t + 1 < NT) stage_B(gB, K, k1, Bn, 0, tid, wave);
        load_afr(Ac, wm, 0, lr, lq, af);
        load_bfr(Bc, wn, 0, lr, lq, b0);
        GBAR(); LGKM0(); SCHED0();
        __builtin_amdgcn_s_setprio(1);
        MFMA_QUAD(0, 0, af, b0);
        __builtin_amdgcn_s_setprio(0);
        GBAR();
        // ---- phase 1: quad (mh0, nh1); stage B1(t+1)
        VMW(4);
        if (t + 1 < NT) stage_B(gB, K, k1, Bn, 1, tid, wave);
        load_bfr(Bc, wn, 1, lr, lq, b1);
        GBAR(); LGKM0(); SCHED0();
        __builtin_amdgcn_s_setprio(1);
        MFMA_QUAD(0, 1, af, b1);
        __builtin_amdgcn_s_setprio(0);
        GBAR();
        // ---- phase 2: quad (mh1, nh1); stage A1(t+1)
        VMW(4);
        if (t + 1 < NT) stage_A(gA, K, k1, An, 1, tid, wave);
        load_afr(Ac, wm, 1, lr, lq, af);
        GBAR(); LGKM0(); SCHED0();
        __builtin_amdgcn_s_setprio(1);
        MFMA_QUAD(1, 1, af, b1);
        __builtin_amdgcn_s_setprio(0);
        GBAR();
        // ---- phase 3: quad (mh1, nh0); stage A0(t+2) into CURRENT A buffer
        // (rows {0-63,128-191} of Ac: last read at this tile's phase 0, and all
        //  waves have passed phase 2's second barrier => those reads retired)
        VMW(4);
        if (t + 2 < NT) stage_A(gA, K, (t + 2) << 6, Ac, 0, tid, wave);
        GBAR();
        __builtin_amdgcn_s_setprio(1);
        MFMA_QUAD(1, 0, af, b0);
        __builtin_amdgcn_s_setprio(0);
        GBAR();
        // swap double buffers
        __bf16* ta = Ac; Ac = An; An = ta;
        __bf16* tb = Bc; Bc = Bn; Bn = tb;
    }

    if constexpr (EPI == 0 || EPI == 2) {
        // repack through LDS (reuse the 128 KiB as a [256][256] bf16 C-tile)
        __bf16* Ct = smem;
#pragma unroll
        for (int m = 0; m < 8; m++)
#pragma unroll
            for (int n = 0; n < 4; n++) {
                const int col = wn * 64 + n * 16 + lr;
                const float bv = bias[bn * 256 + col];
#pragma unroll
                for (int r = 0; r < 4; r++) {
                    float v = acc[m][n][r] + bv;
                    if constexpr (EPI == 2) {
                        // gelu ~= v * sigmoid(1.702 v); pre-act sigma~0.45 so
                        // logistic-vs-erf error is ~1e-3 after W2 contraction
                        const float e = __expf(v * -1.702f);
                        v = v * fast_rcp(1.f + e);
                    }
                    Ct[(wm * 128 + m * 16 + lq * 4 + r) * 256 + col] = (__bf16)v;
                }
            }
        __syncthreads();
#pragma unroll
        for (int j = 0; j < 16; j++) {
            const int ci = j * 512 + tid;
            const int row = ci >> 5, ch = ci & 31;
            *(bf16x8*)(Cb + (size_t)(bm * 256 + row) * N + bn * 256 + ch * 8) =
                *(const bf16x8*)(Ct + row * 256 + ch * 8);
        }
    } else {
#pragma unroll
        for (int m = 0; m < 8; m++) {
            const int row = bm * 256 + wm * 128 + m * 16 + lq * 4;
            int tok[4];
            if constexpr (EPI == 4) {
#pragma unroll
                for (int r = 0; r < 4; r++) tok[r] = prm[row + r];
            }
#pragma unroll
            for (int n = 0; n < 4; n++) {
                const int col = bn * 256 + wn * 64 + n * 16 + lr;
                const float bv = bias[col];
#pragma unroll
                for (int r = 0; r < 4; r++) {
                    const float v = acc[m][n][r] + bv;
                    if constexpr (EPI == 1) {
                        Cf[(size_t)(row + r) * N + col] = v;
                    } else if constexpr (EPI == 3) {
                        const size_t off = (size_t)(row + r) * N + col;
                        Cf[off] = res[off] + v;
                    } else {  // EPI == 4: scatter residual through perm
                        const size_t off = (size_t)tok[r] * N + col;
                        Cf[off] = res[off] + v;
                    }
                }
            }
        }
    }
}

// ---------------------------------------------------------------- attention (MFMA)
// One block per (window, head), 4 waves x 64 q-rows. ONE barrier total (after
// V staging): pbuf is wave-private and cross-lane LDS traffic within a wave
// is ordered by lgkmcnt — no __syncthreads needed in the K-loop or epilogue.
// V is stored TRANSPOSED in LDS with an XOR swizzle on the key-block index so
// PV B-frags are 4x ds_read_b128 per kt (uniform bank spread) instead of 32
// scalar reads. K fragments are software-prefetched one kt ahead.
__global__ __launch_bounds__(256)
void attn_mfma(const __bf16* __restrict__ qkv, __bf16* __restrict__ aout,
               const float* __restrict__ rel_bias) {
    __shared__ __bf16 vsT[HD * WS];      // [d][key-swizzled], 32 KB
    __shared__ __bf16 pbuf[4][64][34];   // wave-private P tile
    const int w = blockIdx.x, h = blockIdx.y;
    const int tid = threadIdx.x;
    const int wave = tid >> 6, lane = tid & 63;
    const int lr = lane & 15, lq = lane >> 4;
    const size_t base = (size_t)w * (WS * 1536) + h * 64;

    // stage V transposed: coalesced global bf16x8 reads, scalar swizzled LDS writes
    for (int c = tid; c < WS * 8; c += 256) {
        const int key = c >> 3, d8 = c & 7;
        bf16x8 vv = *(const bf16x8*)(qkv + base + 1024 + (size_t)key * 1536 + d8 * 8);
#pragma unroll
        for (int jj = 0; jj < 8; jj++) {
            const int d = d8 * 8 + jj;
            vsT[d * WS + (((key >> 3) ^ (d & 31)) << 3) + (key & 7)] = vv[jj];
        }
    }

    const int q0 = wave * 64;
    bf16x8 qf[4][2];
#pragma unroll
    for (int mt = 0; mt < 4; mt++)
#pragma unroll
        for (int kk = 0; kk < 2; kk++)
            qf[mt][kk] = *(const bf16x8*)(qkv + base +
                (size_t)(q0 + mt * 16 + lr) * 1536 + kk * 32 + lq * 8);

    __syncthreads();   // the only block-wide barrier

    floatx4 o[4][4];
    float lsum[4][4];
#pragma unroll
    for (int mt = 0; mt < 4; mt++)
#pragma unroll
        for (int dt = 0; dt < 4; dt++) o[mt][dt] = (floatx4){0.f, 0.f, 0.f, 0.f};
#pragma unroll
    for (int mt = 0; mt < 4; mt++)
#pragma unroll
        for (int r = 0; r < 4; r++) lsum[mt][r] = 0.f;

    const float sc = 0.125f * 1.44269504089f;
    const float bb = rel_bias[h] * 1.44269504089f;
    const __bf16* kp0 = qkv + base + 512;

    // prefetch kt=0 K-frags
    bf16x8 kc[2][2];
#pragma unroll
    for (int nt = 0; nt < 2; nt++) {
        const __bf16* kp = kp0 + (size_t)(nt * 16 + lr) * 1536 + lq * 8;
        kc[nt][0] = *(const bf16x8*)(kp);
        kc[nt][1] = *(const bf16x8*)(kp + 32);
    }

    for (int kt = 0; kt < 8; kt++) {
        const int kbase = kt * 32;
        bf16x8 kn[2][2];
        if (kt < 7) {
#pragma unroll
            for (int nt = 0; nt < 2; nt++) {
                const __bf16* kp = kp0 + (size_t)(kbase + 32 + nt * 16 + lr) * 1536 + lq * 8;
                kn[nt][0] = *(const bf16x8*)(kp);
                kn[nt][1] = *(const bf16x8*)(kp + 32);
            }
        }
        floatx4 s[4][2];
#pragma unroll
        for (int mt = 0; mt < 4; mt++)
#pragma unroll
            for (int nt = 0; nt < 2; nt++) s[mt][nt] = (floatx4){0.f, 0.f, 0.f, 0.f};
#pragma unroll
        for (int nt = 0; nt < 2; nt++)
#pragma unroll
            for (int mt = 0; mt < 4; mt++) {
                s[mt][nt] = __builtin_amdgcn_mfma_f32_16x16x32_bf16(qf[mt][0], kc[nt][0], s[mt][nt], 0, 0, 0);
                s[mt][nt] = __builtin_amdgcn_mfma_f32_16x16x32_bf16(qf[mt][1], kc[nt][1], s[mt][nt], 0, 0, 0);
            }
#pragma unroll
        for (int mt = 0; mt < 4; mt++)
#pragma unroll
            for (int nt = 0; nt < 2; nt++)
#pragma unroll
                for (int r = 0; r < 4; r++) {
                    float e = exp2f(s[mt][nt][r] * sc + bb);
                    lsum[mt][r] += e;
                    pbuf[wave][mt * 16 + lq * 4 + r][nt * 16 + lr] = (__bf16)e;
                }
        // V B-frags: vf[dt][j] = V[kbase+lq*8+j][dt*16+lr] via swizzled vsT
        bf16x8 vf[4];
#pragma unroll
        for (int dt = 0; dt < 4; dt++) {
            const int d = dt * 16 + lr;
            vf[dt] = *(const bf16x8*)(vsT + d * WS +
                                      (((kt * 4 + lq) ^ (d & 31)) << 3));
        }
#pragma unroll
        for (int mt = 0; mt < 4; mt++) {
            bf16x8 pf = *(const bf16x8*)(&pbuf[wave][mt * 16 + lr][lq * 8]);
#pragma unroll
            for (int dt = 0; dt < 4; dt++)
                o[mt][dt] = __builtin_amdgcn_mfma_f32_16x16x32_bf16(pf, vf[dt], o[mt][dt], 0, 0, 0);
        }
#pragma unroll
        for (int nt = 0; nt < 2; nt++) { kc[nt][0] = kn[nt][0]; kc[nt][1] = kn[nt][1]; }
    }

#pragma unroll
    for (int mt = 0; mt < 4; mt++)
#pragma unroll
        for (int r = 0; r < 4; r++) {
            float v = lsum[mt][r];
            v += __shfl_xor(v, 1); v += __shfl_xor(v, 2);
            v += __shfl_xor(v, 4); v += __shfl_xor(v, 8);
            lsum[mt][r] = fast_rcp(v);
        }

    // scale + repack through wave-private pbuf (no barriers needed)
#pragma unroll
    for (int dh = 0; dh < 2; dh++) {
#pragma unroll
        for (int mt = 0; mt < 4; mt++)
#pragma unroll
            for (int dt = 0; dt < 2; dt++)
#pragma unroll
                for (int r = 0; r < 4; r++)
                    pbuf[wave][mt * 16 + lq * 4 + r][dt * 16 + lr] =
                        (__bf16)(o[mt][dh * 2 + dt][r] * lsum[mt][r]);
#pragma unroll
        for (int it = 0; it < 4; it++) {
            const int c = it * 64 + lane;
            const int row = c >> 2, seg = c & 3;
            bf16x8 val = *(const bf16x8*)(&pbuf[wave][row][seg * 8]);
            *(bf16x8*)(aout + (size_t)(w * WS + q0 + row) * CC + h * 64 + dh * 32 + seg * 8) = val;
        }
    }
}

// ---------------------------------------------------------------- launch
extern "C" void kernel_launch(void* const* d_in, const int* in_sizes, int n_in,
                              void* d_out, int out_size, void* d_ws, size_t ws_size,
                              hipStream_t stream) {
    const float* x      = (const float*)d_in[0];
    const float* mesh   = (const float*)d_in[1];
    const float* ln1_g  = (const float*)d_in[2];
    const float* ln1_b  = (const float*)d_in[3];
    const float* qkv_w  = (const float*)d_in[4];
    const float* qkv_b  = (const float*)d_in[5];
    const float* rel_b  = (const float*)d_in[6];
    const float* proj_w = (const float*)d_in[7];
    const float* proj_b = (const float*)d_in[8];
    const float* ln2_g  = (const float*)d_in[9];
    const float* ln2_b  = (const float*)d_in[10];
    const float* w1     = (const float*)d_in[11];
    const float* b1     = (const float*)d_in[12];
    const float* w2     = (const float*)d_in[13];
    const float* b2     = (const float*)d_in[14];
    const int*   wid    = (const int*)d_in[15];

    char* ws = (char*)d_ws;
    int*    perm  = (int*)(ws + 0);
    int*    pos   = (int*)(ws + 165888);
    __bf16* wqkv  = (__bf16*)(ws + 331776);
    __bf16* wproj = (__bf16*)(ws + 1904640);
    __bf16* w1t   = (__bf16*)(ws + 2428928);
    __bf16* w2t   = (__bf16*)(ws + 4526080);
    const size_t BB = 6623232;
    __bf16* hln1 = (__bf16*)(ws + BB);
    __bf16* qkv  = (__bf16*)(ws + BB + 42467328);
    __bf16* aout = (__bf16*)(ws + BB + 169869312);
    __bf16* h2   = (__bf16*)(ws + BB + 84934656);
    __bf16* f1   = (__bf16*)(ws + BB + 127401984);
    float*  xout = (float*)d_out;
    int*    counters = (int*)aout;   // dead region until attention writes aout

    hipMemsetAsync(counters, 0, NW * sizeof(int), stream);
    build_perm_atomic<<<NTOK / 256, 256, 0, stream>>>(wid, perm, pos, counters);

    transpose_bf16<<<(512 * 1536 + 255) / 256, 256, 0, stream>>>(qkv_w, wqkv, 512, 1536);
    transpose_bf16<<<(512 * 512 + 255) / 256, 256, 0, stream>>>(proj_w, wproj, 512, 512);
    transpose_bf16<<<(512 * 2048 + 255) / 256, 256, 0, stream>>>(w1, w1t, 512, 2048);
    transpose_bf16<<<(2048 * 512 + 255) / 256, 256, 0, stream>>>(w2, w2t, 2048, 512);

    ln1_gather<<<NTOK, 64, 0, stream>>>(x, perm, ln1_g, ln1_b, hln1);

    gemm256<0><<<dim3(1536 / 256, NTOK / 256), 512, 0, stream>>>(
        hln1, wqkv, qkv_b, nullptr, nullptr, qkv, NTOK, 1536, 512, nullptr);

    attn_mfma<<<dim3(NW, NH), 256, 0, stream>>>(qkv, aout, rel_b);

    // proj with fused gathered residual: xout[perm[row]] = x[perm[row]] + out
    gemm256<4><<<dim3(512 / 256, NTOK / 256), 512, 0, stream>>>(
        aout, wproj, proj_b, x, xout, nullptr, NTOK, 512, 512, perm);

    ln2_only<<<NTOK, 64, 0, stream>>>(xout, ln2_g, ln2_b, h2);

    gemm256<2><<<dim3(2048 / 256, NTOK / 256), 512, 0, stream>>>(
        h2, w1t, b1, nullptr, nullptr, f1, NTOK, 2048, 512, nullptr);

    gemm256<3><<<dim3(512 / 256, NTOK / 256), 512, 0, stream>>>(
        f1, w2t, b2, xout, xout, nullptr, NTOK, 512, 2048, nullptr);

    hipMemcpyAsync((char*)d_out + (size_t)NTOK * CC * 4, mesh,
                   (size_t)NTOK * 3 * 4, hipMemcpyDeviceToDevice, stream);
}

// Round 5
// 727.289 us; speedup vs baseline: 1.1785x; 1.0512x over previous
//
#include <hip/hip_runtime.h>
#include <hip/hip_bf16.h>
#include <math.h>

// Problem constants (B=1)
#define NW   162
#define WS   256
#define NH   8
#define HD   64
#define CC   512
#define NTOK 41472      // NW*WS
#define HID  2048

typedef __bf16 bf16x8 __attribute__((ext_vector_type(8)));
typedef float  floatx4 __attribute__((ext_vector_type(4)));

__device__ __forceinline__ void gload_lds16(const __bf16* g, __bf16* l) {
    __builtin_amdgcn_global_load_lds((const __attribute__((address_space(1))) void*)g,
                                     (__attribute__((address_space(3))) void*)l,
                                     16, 0, 0);
}
__device__ __forceinline__ float fast_rcp(float x) { return __builtin_amdgcn_rcpf(x); }

#define GBAR()  __builtin_amdgcn_s_barrier()
#define VMW(N)  asm volatile("s_waitcnt vmcnt(" #N ")" ::: "memory")
#define LGKM0() asm volatile("s_waitcnt lgkmcnt(0)" ::: "memory")
#define SCHED0() __builtin_amdgcn_sched_barrier(0)

// ---------------------------------------------------------------- perm build
// Any consistent intra-window order is exact (attention is permutation-
// equivariant within a window; output scattered back through perm).
__global__ __launch_bounds__(256)
void build_perm_atomic(const int* __restrict__ wid, int* __restrict__ perm,
                       int* __restrict__ counters) {
    const int i = blockIdx.x * 256 + threadIdx.x;
    const int w = wid[i];
    const int r = atomicAdd(&counters[w], 1);
    perm[w * WS + r] = i;
}

// ------------------------------------------------------- weight transpose
__global__ void transpose_bf16(const float* __restrict__ in,
                               __bf16* __restrict__ out, int K, int N) {
    int idx = blockIdx.x * 256 + threadIdx.x;
    if (idx >= K * N) return;
    int n = idx / K, k = idx - n * K;
    out[idx] = (__bf16)in[(size_t)k * N + n];
}

// ---------------------------------------------------------------- LN kernels
__global__ __launch_bounds__(64)
void ln1_gather(const float* __restrict__ x, const int* __restrict__ perm,
                const float* __restrict__ g, const float* __restrict__ b,
                __bf16* __restrict__ h) {
    const int j = blockIdx.x, lane = threadIdx.x;
    const int orig = perm[j];
    const float4* xp = (const float4*)(x + (size_t)orig * CC);
    float4 a0 = xp[lane * 2 + 0], a1 = xp[lane * 2 + 1];
    float s  = a0.x + a0.y + a0.z + a0.w + a1.x + a1.y + a1.z + a1.w;
    float sq = a0.x*a0.x + a0.y*a0.y + a0.z*a0.z + a0.w*a0.w
             + a1.x*a1.x + a1.y*a1.y + a1.z*a1.z + a1.w*a1.w;
#pragma unroll
    for (int o = 32; o; o >>= 1) { s += __shfl_xor(s, o); sq += __shfl_xor(sq, o); }
    const float m  = s * (1.f / CC);
    const float rs = rsqrtf(sq * (1.f / CC) - m * m + 1e-5f);
    const float4* g4 = (const float4*)g;  const float4* b4 = (const float4*)b;
    float4 g0 = g4[lane*2+0], g1 = g4[lane*2+1], bb0 = b4[lane*2+0], bb1 = b4[lane*2+1];
    bf16x8 o8;
    o8[0] = (__bf16)((a0.x - m) * rs * g0.x + bb0.x);
    o8[1] = (__bf16)((a0.y - m) * rs * g0.y + bb0.y);
    o8[2] = (__bf16)((a0.z - m) * rs * g0.z + bb0.z);
    o8[3] = (__bf16)((a0.w - m) * rs * g0.w + bb0.w);
    o8[4] = (__bf16)((a1.x - m) * rs * g1.x + bb1.x);
    o8[5] = (__bf16)((a1.y - m) * rs * g1.y + bb1.y);
    o8[6] = (__bf16)((a1.z - m) * rs * g1.z + bb1.z);
    o8[7] = (__bf16)((a1.w - m) * rs * g1.w + bb1.w);
    *(bf16x8*)(h + (size_t)j * CC + lane * 8) = o8;
}

// LN over xout (which already holds x + proj residual), writes bf16 h2.
__global__ __launch_bounds__(64)
void ln2_only(const float* __restrict__ x, const float* __restrict__ g,
              const float* __restrict__ b, __bf16* __restrict__ h2) {
    const int i = blockIdx.x, lane = threadIdx.x;
    const float4* xp = (const float4*)(x + (size_t)i * CC);
    float4 a0 = xp[lane*2+0], a1 = xp[lane*2+1];
    float s  = a0.x + a0.y + a0.z + a0.w + a1.x + a1.y + a1.z + a1.w;
    float sq = a0.x*a0.x + a0.y*a0.y + a0.z*a0.z + a0.w*a0.w
             + a1.x*a1.x + a1.y*a1.y + a1.z*a1.z + a1.w*a1.w;
#pragma unroll
    for (int o = 32; o; o >>= 1) { s += __shfl_xor(s, o); sq += __shfl_xor(sq, o); }
    const float m  = s * (1.f / CC);
    const float rs = rsqrtf(sq * (1.f / CC) - m * m + 1e-5f);
    const float4* g4 = (const float4*)g;  const float4* b4 = (const float4*)b;
    float4 g0 = g4[lane*2+0], g1 = g4[lane*2+1], bb0 = b4[lane*2+0], bb1 = b4[lane*2+1];
    bf16x8 o8;
    o8[0] = (__bf16)((a0.x - m) * rs * g0.x + bb0.x);
    o8[1] = (__bf16)((a0.y - m) * rs * g0.y + bb0.y);
    o8[2] = (__bf16)((a0.z - m) * rs * g0.z + bb0.z);
    o8[3] = (__bf16)((a0.w - m) * rs * g0.w + bb0.w);
    o8[4] = (__bf16)((a1.x - m) * rs * g1.x + bb1.x);
    o8[5] = (__bf16)((a1.y - m) * rs * g1.y + bb1.y);
    o8[6] = (__bf16)((a1.z - m) * rs * g1.z + bb1.z);
    o8[7] = (__bf16)((a1.w - m) * rs * g1.w + bb1.w);
    *(bf16x8*)(h2 + (size_t)i * CC + lane * 8) = o8;
}

// ---------------------------------------------------------------- GEMM 256x256
// 8 waves (2M x 4N), BK=64, 128 KiB LDS (double buffer).  r1-proven staging/
// VMW schedule; post-MFMA barriers REMOVED (hazard analysis: every staged
// set's publish chain is {VMW covering it + pre-MFMA barrier} — B1(t) done at
// ph0's VMW(4), A1(t) at ph1's, A0/B0(t+1) at ph3's — and every slot
// overwrite targets rows whose reads retired >=1 barrier earlier).  4
// barriers/K-tile instead of 8; waves may drift one segment, overlapping
// ds_read/stage issue with other waves' MFMA.  XOR chunk swizzle
// (chunk ^= row&7) on staging source and frag reads — conflict-free
// (SQ_LDS_BANK_CONFLICT == 0 measured).
__device__ __forceinline__ void stage_A(const __bf16* __restrict__ g, int K, int kcol,
                                        __bf16* lds, int h, int tid, int wave) {
    const int sch = ((tid & 7) ^ ((tid >> 3) & 7)) << 3;
#pragma unroll
    for (int j = 0; j < 2; j++) {
        const int rw   = (j * 512 + tid) >> 3;
        const int row  = (rw & 63) + ((rw & 64) << 1) + (h << 6);
        const int rw0  = j * 64 + wave * 8;
        const int row0 = (rw0 & 63) + ((rw0 & 64) << 1) + (h << 6);
        gload_lds16(g + (size_t)row * K + kcol + sch, lds + row0 * 64);
    }
}
__device__ __forceinline__ void stage_B(const __bf16* __restrict__ g, int K, int kcol,
                                        __bf16* lds, int h, int tid, int wave) {
    const int sch = ((tid & 7) ^ ((tid >> 3) & 7)) << 3;
#pragma unroll
    for (int j = 0; j < 2; j++) {
        const int rw   = (j * 512 + tid) >> 3;
        const int row  = (rw & 31) + ((rw >> 5) << 6) + (h << 5);
        const int rw0  = j * 64 + wave * 8;
        const int row0 = (rw0 & 31) + ((rw0 >> 5) << 6) + (h << 5);
        gload_lds16(g + (size_t)row * K + kcol + sch, lds + row0 * 64);
    }
}

__device__ __forceinline__ void load_afr(const __bf16* buf, int wm, int mh,
                                         int lr, int lq, bf16x8 (&af)[4][2]) {
#pragma unroll
    for (int mt = 0; mt < 4; mt++) {
        const __bf16* rp = buf + (wm * 128 + mh * 64 + mt * 16 + lr) * 64;
#pragma unroll
        for (int kk = 0; kk < 2; kk++)
            af[mt][kk] = *(const bf16x8*)(rp + (((kk * 4 + lq) ^ (lr & 7)) << 3));
    }
}
__device__ __forceinline__ void load_bfr(const __bf16* buf, int wn, int nh,
                                         int lr, int lq, bf16x8 (&bf)[2][2]) {
#pragma unroll
    for (int nt = 0; nt < 2; nt++) {
        const __bf16* rp = buf + (wn * 64 + nh * 32 + nt * 16 + lr) * 64;
#pragma unroll
        for (int kk = 0; kk < 2; kk++)
            bf[nt][kk] = *(const bf16x8*)(rp + (((kk * 4 + lq) ^ (lr & 7)) << 3));
    }
}

#define MFMA_QUAD(MH, NH, AF, BF)                                              \
    _Pragma("unroll") for (int kk_ = 0; kk_ < 2; kk_++)                        \
    _Pragma("unroll") for (int mt_ = 0; mt_ < 4; mt_++)                        \
    _Pragma("unroll") for (int nt_ = 0; nt_ < 2; nt_++)                        \
        acc[(MH) * 4 + mt_][(NH) * 2 + nt_] =                                  \
            __builtin_amdgcn_mfma_f32_16x16x32_bf16(                           \
                AF[mt_][kk_], BF[nt_][kk_],                                    \
                acc[(MH) * 4 + mt_][(NH) * 2 + nt_], 0, 0, 0);

// EPI: 0 = +bias -> bf16; 1 = +bias -> f32; 2 = +bias, GELU(logistic) -> bf16;
//      3 = res + acc + bias -> f32 (in-place residual);
//      4 = gathered residual: Cf[perm[row]] = res[perm[row]] + acc + bias.
template <int EPI>
__device__ __forceinline__
void gemm_body(const __bf16* __restrict__ A, const __bf16* __restrict__ Bt,
               const float* __restrict__ bias, const float* __restrict__ res,
               float* __restrict__ Cf, __bf16* __restrict__ Cb,
               int M, int N, int K, const int* __restrict__ prm) {
    __shared__ __bf16 smem[65536];   // 128 KiB: A dbuf 64K | B dbuf 64K; epilogue reuses as C-tile
    __bf16* Ac = smem;
    __bf16* An = smem + 16384;
    __bf16* Bc = smem + 32768;
    __bf16* Bn = smem + 49152;

    const int tid  = threadIdx.x;
    const int wave = tid >> 6;
    const int lane = tid & 63;
    const int wm = wave >> 2, wn = wave & 3;
    const int lr = lane & 15, lq = lane >> 4;

    // bijective XCD-aware swizzle (m204 form; grids here are not all %8==0)
    const int gx  = gridDim.x;
    const int nwg = gx * gridDim.y;
    const int orig = blockIdx.y * gx + blockIdx.x;
    const int q8 = nwg >> 3, r8 = nwg & 7;
    const int xcd = orig & 7, oi = orig >> 3;
    const int wgid = (xcd < r8 ? xcd * (q8 + 1) : r8 * (q8 + 1) + (xcd - r8) * q8) + oi;
    const int bm = wgid / gx, bn = wgid - bm * gx;

    const __bf16* gA = A  + (size_t)bm * 256 * K;
    const __bf16* gB = Bt + (size_t)bn * 256 * K;
    const int NT = K >> 6;

    floatx4 acc[8][4];
#pragma unroll
    for (int i = 0; i < 8; i++)
#pragma unroll
        for (int j = 0; j < 4; j++) acc[i][j] = (floatx4){0.f, 0.f, 0.f, 0.f};

    // prologue (issue order defines vmcnt window): A0(0),B0(0),B1(0),A1(0),A0(1)
    stage_A(gA, K, 0, Ac, 0, tid, wave);
    stage_B(gB, K, 0, Bc, 0, tid, wave);
    stage_B(gB, K, 0, Bc, 1, tid, wave);
    stage_A(gA, K, 0, Ac, 1, tid, wave);
    if (NT > 1) stage_A(gA, K, 64, An, 0, tid, wave);
    VMW(4);
    GBAR();

    bf16x8 af[4][2], b0[2][2], b1[2][2];

    for (int t = 0; t < NT; t++) {
        const int k1 = (t + 1) << 6;
        // ---- phase 0: quad (mh0, nh0); stage B0(t+1).
        //      VMW(4) completes B0(t),B1(t) (and older); barrier publishes.
        if (t == NT - 1) { VMW(0); } else { VMW(4); }
        if (t + 1 < NT) stage_B(gB, K, k1, Bn, 0, tid, wave);
        load_afr(Ac, wm, 0, lr, lq, af);
        load_bfr(Bc, wn, 0, lr, lq, b0);
        GBAR(); LGKM0(); SCHED0();
        __builtin_amdgcn_s_setprio(1);
        MFMA_QUAD(0, 0, af, b0);
        __builtin_amdgcn_s_setprio(0);
        // ---- phase 1: quad (mh0, nh1); stage B1(t+1).
        //      VMW(4) completes A1(t); barrier publishes for ph2's reads.
        VMW(4);
        if (t + 1 < NT) stage_B(gB, K, k1, Bn, 1, tid, wave);
        load_bfr(Bc, wn, 1, lr, lq, b1);
        GBAR(); LGKM0(); SCHED0();
        __builtin_amdgcn_s_setprio(1);
        MFMA_QUAD(0, 1, af, b1);
        __builtin_amdgcn_s_setprio(0);
        // ---- phase 2: quad (mh1, nh1); stage A1(t+1)
        VMW(4);
        if (t + 1 < NT) stage_A(gA, K, k1, An, 1, tid, wave);
        load_afr(Ac, wm, 1, lr, lq, af);
        GBAR(); LGKM0(); SCHED0();
        __builtin_amdgcn_s_setprio(1);
        MFMA_QUAD(1, 1, af, b1);
        __builtin_amdgcn_s_setprio(0);
        // ---- phase 3: quad (mh1, nh0); stage A0(t+2) into CURRENT A buffer
        //      (rows read only at ph0 of this tile; those ds_reads retired at
        //      ph0's LGKM0, and ph1/ph2 barriers separate them from this
        //      write).  VMW(4) completes A0(t+1),B0(t+1); barrier publishes
        //      them for the next tile's ph0 reads.
        VMW(4);
        if (t + 2 < NT) stage_A(gA, K, (t + 2) << 6, Ac, 0, tid, wave);
        GBAR();
        __builtin_amdgcn_s_setprio(1);
        MFMA_QUAD(1, 0, af, b0);
        __builtin_amdgcn_s_setprio(0);
        // swap double buffers (no barrier: next phase-0 barrier precedes any
        // cross-wave visibility requirement)
        __bf16* ta = Ac; Ac = An; An = ta;
        __bf16* tb = Bc; Bc = Bn; Bn = tb;
    }

    if constexpr (EPI == 0 || EPI == 2) {
        // repack through LDS (reuse the 128 KiB as a [256][256] bf16 C-tile).
        // Barrier first: other waves may still be ds_reading their last-tile
        // fragments from smem (no post-MFMA barrier in the loop anymore).
        GBAR();
        __bf16* Ct = smem;
#pragma unroll
        for (int m = 0; m < 8; m++)
#pragma unroll
            for (int n = 0; n < 4; n++) {
                const int col = wn * 64 + n * 16 + lr;
                const float bv = bias[bn * 256 + col];
#pragma unroll
                for (int r = 0; r < 4; r++) {
                    float v = acc[m][n][r] + bv;
                    if constexpr (EPI == 2) {
                        // gelu ~= v * sigmoid(1.702 v); pre-act sigma~0.45 so
                        // logistic-vs-erf error is ~1e-3 after W2 contraction
                        const float e = __expf(v * -1.702f);
                        v = v * fast_rcp(1.f + e);
                    }
                    Ct[(wm * 128 + m * 16 + lq * 4 + r) * 256 + col] = (__bf16)v;
                }
            }
        __syncthreads();
#pragma unroll
        for (int j = 0; j < 16; j++) {
            const int ci = j * 512 + tid;
            const int row = ci >> 5, ch = ci & 31;
            *(bf16x8*)(Cb + (size_t)(bm * 256 + row) * N + bn * 256 + ch * 8) =
                *(const bf16x8*)(Ct + row * 256 + ch * 8);
        }
    } else {
#pragma unroll
        for (int m = 0; m < 8; m++) {
            const int row = bm * 256 + wm * 128 + m * 16 + lq * 4;
            int tok[4];
            if constexpr (EPI == 4) {
#pragma unroll
                for (int r = 0; r < 4; r++) tok[r] = prm[row + r];
            }
#pragma unroll
            for (int n = 0; n < 4; n++) {
                const int col = bn * 256 + wn * 64 + n * 16 + lr;
                const float bv = bias[col];
#pragma unroll
                for (int r = 0; r < 4; r++) {
                    const float v = acc[m][n][r] + bv;
                    if constexpr (EPI == 1) {
                        Cf[(size_t)(row + r) * N + col] = v;
                    } else if constexpr (EPI == 3) {
                        const size_t off = (size_t)(row + r) * N + col;
                        Cf[off] = res[off] + v;
                    } else {  // EPI == 4: scatter residual through perm
                        const size_t off = (size_t)tok[r] * N + col;
                        Cf[off] = res[off] + v;
                    }
                }
            }
        }
    }
}

// Distinct names per stage so the profiler's top-5 shows the true split.
__global__ __launch_bounds__(512, 2)
void gemm_qkv(const __bf16* __restrict__ A, const __bf16* __restrict__ Bt,
              const float* __restrict__ bias, __bf16* __restrict__ Cb, int N, int K) {
    gemm_body<0>(A, Bt, bias, nullptr, nullptr, Cb, NTOK, N, K, nullptr);
}
__global__ __launch_bounds__(512, 2)
void gemm_proj(const __bf16* __restrict__ A, const __bf16* __restrict__ Bt,
               const float* __restrict__ bias, const float* __restrict__ res,
               float* __restrict__ Cf, const int* __restrict__ prm, int N, int K) {
    gemm_body<4>(A, Bt, bias, res, Cf, nullptr, NTOK, N, K, prm);
}
__global__ __launch_bounds__(512, 2)
void gemm_ffn1(const __bf16* __restrict__ A, const __bf16* __restrict__ Bt,
               const float* __restrict__ bias, __bf16* __restrict__ Cb, int N, int K) {
    gemm_body<2>(A, Bt, bias, nullptr, nullptr, Cb, NTOK, N, K, nullptr);
}
__global__ __launch_bounds__(512, 2)
void gemm_ffn2(const __bf16* __restrict__ A, const __bf16* __restrict__ Bt,
               const float* __restrict__ bias, const float* __restrict__ res,
               float* __restrict__ Cf, int N, int K) {
    gemm_body<3>(A, Bt, bias, res, Cf, nullptr, NTOK, N, K, nullptr);
}

// ---------------------------------------------------------------- attention (MFMA)
// One block per (window, head), 4 waves x 64 q-rows. ONE barrier total (after
// V staging): pbuf is wave-private and cross-lane LDS traffic within a wave
// is ordered by lgkmcnt — no __syncthreads needed in the K-loop or epilogue.
// V is stored TRANSPOSED in LDS with an XOR swizzle on the key-block index so
// PV B-frags are 4x ds_read_b128 per kt (uniform bank spread) instead of 32
// scalar reads. K fragments are software-prefetched one kt ahead.
__global__ __launch_bounds__(256)
void attn_mfma(const __bf16* __restrict__ qkv, __bf16* __restrict__ aout,
               const float* __restrict__ rel_bias) {
    __shared__ __bf16 vsT[HD * WS];      // [d][key-swizzled], 32 KB
    __shared__ __bf16 pbuf[4][64][34];   // wave-private P tile
    const int w = blockIdx.x, h = blockIdx.y;
    const int tid = threadIdx.x;
    const int wave = tid >> 6, lane = tid & 63;
    const int lr = lane & 15, lq = lane >> 4;
    const size_t base = (size_t)w * (WS * 1536) + h * 64;

    // stage V transposed: coalesced global bf16x8 reads, scalar swizzled LDS writes
    for (int c = tid; c < WS * 8; c += 256) {
        const int key = c >> 3, d8 = c & 7;
        bf16x8 vv = *(const bf16x8*)(qkv + base + 1024 + (size_t)key * 1536 + d8 * 8);
#pragma unroll
        for (int jj = 0; jj < 8; jj++) {
            const int d = d8 * 8 + jj;
            vsT[d * WS + (((key >> 3) ^ (d & 31)) << 3) + (key & 7)] = vv[jj];
        }
    }

    const int q0 = wave * 64;
    bf16x8 qf[4][2];
#pragma unroll
    for (int mt = 0; mt < 4; mt++)
#pragma unroll
        for (int kk = 0; kk < 2; kk++)
            qf[mt][kk] = *(const bf16x8*)(qkv + base +
                (size_t)(q0 + mt * 16 + lr) * 1536 + kk * 32 + lq * 8);

    __syncthreads();   // the only block-wide barrier

    floatx4 o[4][4];
    float lsum[4][4];
#pragma unroll
    for (int mt = 0; mt < 4; mt++)
#pragma unroll
        for (int dt = 0; dt < 4; dt++) o[mt][dt] = (floatx4){0.f, 0.f, 0.f, 0.f};
#pragma unroll
    for (int mt = 0; mt < 4; mt++)
#pragma unroll
        for (int r = 0; r < 4; r++) lsum[mt][r] = 0.f;

    const float sc = 0.125f * 1.44269504089f;
    const float bb = rel_bias[h] * 1.44269504089f;
    const __bf16* kp0 = qkv + base + 512;

    // prefetch kt=0 K-frags
    bf16x8 kc[2][2];
#pragma unroll
    for (int nt = 0; nt < 2; nt++) {
        const __bf16* kp = kp0 + (size_t)(nt * 16 + lr) * 1536 + lq * 8;
        kc[nt][0] = *(const bf16x8*)(kp);
        kc[nt][1] = *(const bf16x8*)(kp + 32);
    }

    for (int kt = 0; kt < 8; kt++) {
        const int kbase = kt * 32;
        bf16x8 kn[2][2];
        if (kt < 7) {
#pragma unroll
            for (int nt = 0; nt < 2; nt++) {
                const __bf16* kp = kp0 + (size_t)(kbase + 32 + nt * 16 + lr) * 1536 + lq * 8;
                kn[nt][0] = *(const bf16x8*)(kp);
                kn[nt][1] = *(const bf16x8*)(kp + 32);
            }
        }
        floatx4 s[4][2];
#pragma unroll
        for (int mt = 0; mt < 4; mt++)
#pragma unroll
            for (int nt = 0; nt < 2; nt++) s[mt][nt] = (floatx4){0.f, 0.f, 0.f, 0.f};
#pragma unroll
        for (int nt = 0; nt < 2; nt++)
#pragma unroll
            for (int mt = 0; mt < 4; mt++) {
                s[mt][nt] = __builtin_amdgcn_mfma_f32_16x16x32_bf16(qf[mt][0], kc[nt][0], s[mt][nt], 0, 0, 0);
                s[mt][nt] = __builtin_amdgcn_mfma_f32_16x16x32_bf16(qf[mt][1], kc[nt][1], s[mt][nt], 0, 0, 0);
            }
#pragma unroll
        for (int mt = 0; mt < 4; mt++)
#pragma unroll
            for (int nt = 0; nt < 2; nt++)
#pragma unroll
                for (int r = 0; r < 4; r++) {
                    float e = exp2f(s[mt][nt][r] * sc + bb);
                    lsum[mt][r] += e;
                    pbuf[wave][mt * 16 + lq * 4 + r][nt * 16 + lr] = (__bf16)e;
                }
        // V B-frags: vf[dt][j] = V[kbase+lq*8+j][dt*16+lr] via swizzled vsT
        bf16x8 vf[4];
#pragma unroll
        for (int dt = 0; dt < 4; dt++) {
            const int d = dt * 16 + lr;
            vf[dt] = *(const bf16x8*)(vsT + d * WS +
                                      (((kt * 4 + lq) ^ (d & 31)) << 3));
        }
#pragma unroll
        for (int mt = 0; mt < 4; mt++) {
            bf16x8 pf = *(const bf16x8*)(&pbuf[wave][mt * 16 + lr][lq * 8]);
#pragma unroll
            for (int dt = 0; dt < 4; dt++)
                o[mt][dt] = __builtin_amdgcn_mfma_f32_16x16x32_bf16(pf, vf[dt], o[mt][dt], 0, 0, 0);
        }
#pragma unroll
        for (int nt = 0; nt < 2; nt++) { kc[nt][0] = kn[nt][0]; kc[nt][1] = kn[nt][1]; }
    }

#pragma unroll
    for (int mt = 0; mt < 4; mt++)
#pragma unroll
        for (int r = 0; r < 4; r++) {
            float v = lsum[mt][r];
            v += __shfl_xor(v, 1); v += __shfl_xor(v, 2);
            v += __shfl_xor(v, 4); v += __shfl_xor(v, 8);
            lsum[mt][r] = fast_rcp(v);
        }

    // scale + repack through wave-private pbuf (no barriers needed)
#pragma unroll
    for (int dh = 0; dh < 2; dh++) {
#pragma unroll
        for (int mt = 0; mt < 4; mt++)
#pragma unroll
            for (int dt = 0; dt < 2; dt++)
#pragma unroll
                for (int r = 0; r < 4; r++)
                    pbuf[wave][mt * 16 + lq * 4 + r][dt * 16 + lr] =
                        (__bf16)(o[mt][dh * 2 + dt][r] * lsum[mt][r]);
#pragma unroll
        for (int it = 0; it < 4; it++) {
            const int c = it * 64 + lane;
            const int row = c >> 2, seg = c & 3;
            bf16x8 val = *(const bf16x8*)(&pbuf[wave][row][seg * 8]);
            *(bf16x8*)(aout + (size_t)(w * WS + q0 + row) * CC + h * 64 + dh * 32 + seg * 8) = val;
        }
    }
}

// ---------------------------------------------------------------- launch
extern "C" void kernel_launch(void* const* d_in, const int* in_sizes, int n_in,
                              void* d_out, int out_size, void* d_ws, size_t ws_size,
                              hipStream_t stream) {
    const float* x      = (const float*)d_in[0];
    const float* mesh   = (const float*)d_in[1];
    const float* ln1_g  = (const float*)d_in[2];
    const float* ln1_b  = (const float*)d_in[3];
    const float* qkv_w  = (const float*)d_in[4];
    const float* qkv_b  = (const float*)d_in[5];
    const float* rel_b  = (const float*)d_in[6];
    const float* proj_w = (const float*)d_in[7];
    const float* proj_b = (const float*)d_in[8];
    const float* ln2_g  = (const float*)d_in[9];
    const float* ln2_b  = (const float*)d_in[10];
    const float* w1     = (const float*)d_in[11];
    const float* b1     = (const float*)d_in[12];
    const float* w2     = (const float*)d_in[13];
    const float* b2     = (const float*)d_in[14];
    const int*   wid    = (const int*)d_in[15];

    char* ws = (char*)d_ws;
    int*    perm  = (int*)(ws + 0);
    __bf16* wqkv  = (__bf16*)(ws + 331776);
    __bf16* wproj = (__bf16*)(ws + 1904640);
    __bf16* w1t   = (__bf16*)(ws + 2428928);
    __bf16* w2t   = (__bf16*)(ws + 4526080);
    const size_t BB = 6623232;
    __bf16* hln1 = (__bf16*)(ws + BB);
    __bf16* qkv  = (__bf16*)(ws + BB + 42467328);
    __bf16* aout = (__bf16*)(ws + BB + 169869312);
    __bf16* h2   = (__bf16*)(ws + BB + 84934656);
    __bf16* f1   = (__bf16*)(ws + BB + 127401984);
    float*  xout = (float*)d_out;
    int*    counters = (int*)aout;   // dead region until attention writes aout

    hipMemsetAsync(counters, 0, NW * sizeof(int), stream);
    build_perm_atomic<<<NTOK / 256, 256, 0, stream>>>(wid, perm, counters);

    transpose_bf16<<<(512 * 1536 + 255) / 256, 256, 0, stream>>>(qkv_w, wqkv, 512, 1536);
    transpose_bf16<<<(512 * 512 + 255) / 256, 256, 0, stream>>>(proj_w, wproj, 512, 512);
    transpose_bf16<<<(512 * 2048 + 255) / 256, 256, 0, stream>>>(w1, w1t, 512, 2048);
    transpose_bf16<<<(2048 * 512 + 255) / 256, 256, 0, stream>>>(w2, w2t, 2048, 512);

    ln1_gather<<<NTOK, 64, 0, stream>>>(x, perm, ln1_g, ln1_b, hln1);

    gemm_qkv<<<dim3(1536 / 256, NTOK / 256), 512, 0, stream>>>(
        hln1, wqkv, qkv_b, qkv, 1536, 512);

    attn_mfma<<<dim3(NW, NH), 256, 0, stream>>>(qkv, aout, rel_b);

    // proj with fused gathered residual: xout[perm[row]] = x[perm[row]] + out
    gemm_proj<<<dim3(512 / 256, NTOK / 256), 512, 0, stream>>>(
        aout, wproj, proj_b, x, xout, perm, 512, 512);

    ln2_only<<<NTOK, 64, 0, stream>>>(xout, ln2_g, ln2_b, h2);

    gemm_ffn1<<<dim3(2048 / 256, NTOK / 256), 512, 0, stream>>>(
        h2, w1t, b1, f1, 2048, 512);

    gemm_ffn2<<<dim3(512 / 256, NTOK / 256), 512, 0, stream>>>(
        f1, w2t, b2, xout, xout, 512, 2048);

    hipMemcpyAsync((char*)d_out + (size_t)NTOK * CC * 4, mesh,
                   (size_t)NTOK * 3 * 4, hipMemcpyDeviceToDevice, stream);
}